// Round 1
// baseline (138.722 us; speedup 1.0000x reference)
//
#include <hip/hip_runtime.h>
#include <hip/hip_fp16.h>

// ---- types ----
typedef _Float16 f16x8 __attribute__((ext_vector_type(8)));
typedef _Float16 f16x4 __attribute__((ext_vector_type(4)));
typedef float f32x4 __attribute__((ext_vector_type(4)));

// Problem constants
#define NN     16384
#define NS_    16384
#define KK     32
#define CS_    256
#define MM     64
#define RTOT   (NN * KK)        // 524288 rows

// ---------------------------------------------------------------------------
// prep 1: source f32 -> f16   (16384x256 = 4,194,304 elems, 8 per thread)
// ---------------------------------------------------------------------------
__global__ void prep_src(const float* __restrict__ src, _Float16* __restrict__ dst) {
    int i = blockIdx.x * 256 + threadIdx.x;      // 524288 threads
    int base = i * 8;
    f32x4 a = *(const f32x4*)(src + base);
    f32x4 b = *(const f32x4*)(src + base + 4);
    f16x8 h;
    h[0] = (_Float16)a[0]; h[1] = (_Float16)a[1]; h[2] = (_Float16)a[2]; h[3] = (_Float16)a[3];
    h[4] = (_Float16)b[0]; h[5] = (_Float16)b[1]; h[6] = (_Float16)b[2]; h[7] = (_Float16)b[3];
    *(f16x8*)(dst + base) = h;
}

// ---------------------------------------------------------------------------
// prep 2: WcT f16 [128][256]  (row o<64: W_s col o; row 64+o: mean_m W_lin col o)
//         + b_mean f32 [64]
// ---------------------------------------------------------------------------
__global__ void prep_weights(const float* __restrict__ W_lin, const float* __restrict__ b_lin,
                             const float* __restrict__ W_s,
                             _Float16* __restrict__ WcT, float* __restrict__ bmean) {
    int tid = blockIdx.x * 256 + threadIdx.x;    // 32768 threads
    if (tid < 16384) {
        int c = tid >> 6, o = tid & 63;
        WcT[o * 256 + c] = (_Float16)W_s[c * 64 + o];
    } else {
        int t = tid - 16384;
        int c = t >> 6, o = t & 63;
        float s = 0.f;
        #pragma unroll 8
        for (int m = 0; m < 64; ++m) s += W_lin[m * 16384 + c * 64 + o];
        WcT[(64 + o) * 256 + c] = (_Float16)(s * (1.f / 64.f));
    }
    if (tid < 64) {
        float s = 0.f;
        #pragma unroll 8
        for (int m = 0; m < 64; ++m) s += b_lin[m * 64 + tid];
        bmean[tid] = s * (1.f / 64.f);
    }
}

// ---------------------------------------------------------------------------
// prep 3: tl[n][m] = target[n,:] . W_t[:,m] + b_s[m] + b_t[m]    (f32)
// one wave per row n, lane = m
// ---------------------------------------------------------------------------
__global__ void prep_tl(const float* __restrict__ target, const float* __restrict__ W_t,
                        const float* __restrict__ b_s, const float* __restrict__ b_t,
                        float* __restrict__ tl) {
    int w = threadIdx.x >> 6, l = threadIdx.x & 63;
    int n = blockIdx.x * 4 + w;
    float acc = b_s[l] + b_t[l];
    const float* trow = target + n * 256;
    #pragma unroll 4
    for (int c = 0; c < 256; c += 4) {
        f32x4 tv = *(const f32x4*)(trow + c);
        acc += tv[0] * W_t[(c + 0) * 64 + l];
        acc += tv[1] * W_t[(c + 1) * 64 + l];
        acc += tv[2] * W_t[(c + 2) * 64 + l];
        acc += tv[3] * W_t[(c + 3) * 64 + l];
    }
    tl[n * 64 + l] = acc;
}

// ---------------------------------------------------------------------------
// main: GEMM [524288 x 256] x [256 x 128] + softmax epilogue
// 512 threads (8 waves). Block tile: 256 rows x 128 cols; wave: 32 rows x 128.
// B in LDS (64KB, XOR-swizzled); A fragments straight from global (no barrier
// in the K-loop). MFMA 16x16x32 f16.
// ---------------------------------------------------------------------------
__global__ __launch_bounds__(512, 4)
void main_kernel(const _Float16* __restrict__ src16, const int* __restrict__ neighbors,
                 const _Float16* __restrict__ WcT, const float* __restrict__ tl,
                 const float* __restrict__ bmean, float* __restrict__ out) {
    __shared__ _Float16 lds[32768];   // 64 KiB: BT[o][c], byte ^= (o&7)<<4

    const int tid = threadIdx.x;

    // ---- stage B (swizzled) ----
    #pragma unroll
    for (int i = 0; i < 8; ++i) {
        int chunk = tid + i * 512;              // 4096 x 16B chunks
        int o   = chunk >> 5;                   // 32 chunks per 512B row
        int c16 = chunk & 31;
        f16x8 v = *(const f16x8*)(WcT + chunk * 8);
        int dstbyte = o * 512 + ((c16 * 16) ^ ((o & 7) << 4));
        *(f16x8*)((char*)lds + dstbyte) = v;
    }
    __syncthreads();

    const int w   = tid >> 6;
    const int l   = tid & 63;
    const int l15 = l & 15;
    const int lq  = l >> 4;
    const int rowbase = blockIdx.x * 256 + w * 32;

    // A fragment pointers (rows of the two 16-row M-tiles this wave owns)
    const int r0 = rowbase + l15;
    const int r1 = rowbase + 16 + l15;
    const _Float16* ap0 = src16 + (size_t)neighbors[r0] * 256 + lq * 8;
    const _Float16* ap1 = src16 + (size_t)neighbors[r1] * 256 + lq * 8;

    // B base byte-addresses per N-tile (swizzled); kstep applies ^ (s*64)
    int bbase[8];
    #pragma unroll
    for (int nt = 0; nt < 8; ++nt) {
        int o = nt * 16 + l15;
        bbase[nt] = o * 512 + ((lq * 16) ^ ((o & 7) << 4));
    }

    f32x4 acc[2][8] = {};

    #pragma unroll
    for (int s = 0; s < 8; ++s) {
        f16x8 a0 = *(const f16x8*)(ap0 + s * 32);
        f16x8 a1 = *(const f16x8*)(ap1 + s * 32);
        #pragma unroll
        for (int nt = 0; nt < 8; ++nt) {
            f16x8 b = *(const f16x8*)((char*)lds + (bbase[nt] ^ (s * 64)));
            acc[0][nt] = __builtin_amdgcn_mfma_f32_16x16x32_f16(a0, b, acc[0][nt], 0, 0, 0);
            acc[1][nt] = __builtin_amdgcn_mfma_f32_16x16x32_f16(a1, b, acc[1][nt], 0, 0, 0);
        }
    }

    // ---- epilogue: softmax over 64 logit cols, multiply proj, store ----
    const int n = blockIdx.x * 8 + w;           // one target node per wave
    float tlv[4], bmv[4];
    #pragma unroll
    for (int nt = 0; nt < 4; ++nt) {
        tlv[nt] = tl[n * 64 + nt * 16 + l15];
        bmv[nt] = bmean[nt * 16 + l15];
    }

    #pragma unroll
    for (int m = 0; m < 2; ++m) {
        #pragma unroll
        for (int j = 0; j < 4; ++j) {
            const int r = rowbase + m * 16 + lq * 4 + j;
            float lg[4];
            float mx = -1e30f;
            #pragma unroll
            for (int nt = 0; nt < 4; ++nt) {
                lg[nt] = acc[m][nt][j] + tlv[nt];
                mx = fmaxf(mx, lg[nt]);
            }
            #pragma unroll
            for (int d = 1; d < 16; d <<= 1) mx = fmaxf(mx, __shfl_xor(mx, d));
            float e[4], sum = 0.f;
            #pragma unroll
            for (int nt = 0; nt < 4; ++nt) {
                e[nt] = __expf(lg[nt] - mx);
                sum += e[nt];
            }
            #pragma unroll
            for (int d = 1; d < 16; d <<= 1) sum += __shfl_xor(sum, d);
            const float inv = 1.0f / sum;
            float* orow = out + (size_t)r * 64;
            #pragma unroll
            for (int nt = 0; nt < 4; ++nt) {
                float a = e[nt] * inv;
                orow[nt * 16 + l15] = a * (acc[m][nt + 4][j] + bmv[nt]);
            }
        }
    }
}

// ---------------------------------------------------------------------------
extern "C" void kernel_launch(void* const* d_in, const int* in_sizes, int n_in,
                              void* d_out, int out_size, void* d_ws, size_t ws_size,
                              hipStream_t stream) {
    const float* source    = (const float*)d_in[0];
    const float* target    = (const float*)d_in[1];
    const int*   neighbors = (const int*)d_in[2];
    const float* W_lin     = (const float*)d_in[3];
    const float* b_lin     = (const float*)d_in[4];
    const float* W_s       = (const float*)d_in[5];
    const float* b_s       = (const float*)d_in[6];
    const float* W_t       = (const float*)d_in[7];
    const float* b_t       = (const float*)d_in[8];

    char* ws = (char*)d_ws;
    _Float16* src16 = (_Float16*)ws;                         // 8 MiB
    _Float16* WcT   = (_Float16*)(ws + 8388608);             // 64 KiB
    float*    bmean = (float*)(ws + 8388608 + 65536);        // 256 B
    float*    tl    = (float*)(ws + 8388608 + 65536 + 256);  // 4 MiB
    float*    out   = (float*)d_out;

    prep_src<<<2048, 256, 0, stream>>>(source, src16);
    prep_weights<<<128, 256, 0, stream>>>(W_lin, b_lin, W_s, WcT, bmean);
    prep_tl<<<4096, 256, 0, stream>>>(target, W_t, b_s, b_t, tl);
    main_kernel<<<2048, 512, 0, stream>>>(src16, neighbors, WcT, tl, bmean, out);
}

// Round 2
// 98.658 us; speedup vs baseline: 1.4061x; 1.4061x over previous
//
#include <hip/hip_runtime.h>
#include <hip/hip_fp16.h>

// ---- types ----
typedef _Float16 f16x8 __attribute__((ext_vector_type(8)));
typedef float f32x4 __attribute__((ext_vector_type(4)));

// ---------------------------------------------------------------------------
// prep: f32 -> f16 convert, 8 elems/thread (launch: nelems/2048 blocks x 256)
// ---------------------------------------------------------------------------
__global__ void cvt_f16(const float* __restrict__ src, _Float16* __restrict__ dst) {
    int i = blockIdx.x * 256 + threadIdx.x;
    int base = i * 8;
    f32x4 a = *(const f32x4*)(src + base);
    f32x4 b = *(const f32x4*)(src + base + 4);
    f16x8 h;
    h[0] = (_Float16)a[0]; h[1] = (_Float16)a[1]; h[2] = (_Float16)a[2]; h[3] = (_Float16)a[3];
    h[4] = (_Float16)b[0]; h[5] = (_Float16)b[1]; h[6] = (_Float16)b[2]; h[7] = (_Float16)b[3];
    *(f16x8*)(dst + base) = h;
}

// ---------------------------------------------------------------------------
// prep: WcT f16 [128][256] (row o<64: W_s col o; row 64+o: mean_m W_lin col o)
//       Wt16 f16 [64][256] (W_t transposed)
//       bmean f32 [64]
// ---------------------------------------------------------------------------
__global__ void prep_weights(const float* __restrict__ W_lin, const float* __restrict__ b_lin,
                             const float* __restrict__ W_s, const float* __restrict__ W_t,
                             _Float16* __restrict__ WcT, _Float16* __restrict__ Wt16,
                             float* __restrict__ bmean) {
    int tid = blockIdx.x * 256 + threadIdx.x;    // 32768 threads
    if (tid < 16384) {
        int c = tid >> 6, o = tid & 63;
        WcT[o * 256 + c]  = (_Float16)W_s[c * 64 + o];
        Wt16[o * 256 + c] = (_Float16)W_t[c * 64 + o];
    } else {
        int t = tid - 16384;
        int c = t >> 6, o = t & 63;
        float s = 0.f;
        #pragma unroll 8
        for (int m = 0; m < 64; ++m) s += W_lin[m * 16384 + c * 64 + o];
        WcT[(64 + o) * 256 + c] = (_Float16)(s * (1.f / 64.f));
    }
    if (tid < 64) {
        float s = 0.f;
        #pragma unroll 8
        for (int m = 0; m < 64; ++m) s += b_lin[m * 64 + tid];
        bmean[tid] = s * (1.f / 64.f);
    }
}

// ---------------------------------------------------------------------------
// prep: tl[n][m] = target[n,:] . W_t[:,m] + b_s[m] + b_t[m]  via MFMA
// 64 blocks x 256 thr (4 waves); block: 256 rows x 64 cols; wave: 64 rows.
// LDS: 32 fragments (nt<4, s<8) x 64 lanes x 16B = 32 KiB, fragment-major.
// ---------------------------------------------------------------------------
__global__ __launch_bounds__(256, 4)
void prep_tl(const _Float16* __restrict__ tgt16, const _Float16* __restrict__ Wt16,
             const float* __restrict__ b_s, const float* __restrict__ b_t,
             float* __restrict__ tl) {
    __shared__ _Float16 lds[16384];   // 32 KiB

    const int tid = threadIdx.x;
    const int w = tid >> 6, l = tid & 63;
    const int l15 = l & 15, lq = l >> 4;
    const int rowbase = blockIdx.x * 256 + w * 64;

    const _Float16* ap[4];
    f16x8 ac[4];
    #pragma unroll
    for (int m = 0; m < 4; ++m) {
        ap[m] = tgt16 + (size_t)(rowbase + m * 16 + l15) * 256 + lq * 8;
        ac[m] = *(const f16x8*)ap[m];
    }

    // stage W_tT fragment-major: wave w, iter i stages fragment fi = i*4 + w
    #pragma unroll
    for (int i = 0; i < 8; ++i) {
        int fi = i * 4 + w;
        int nt = fi >> 3, s = fi & 7;
        f16x8 v = *(const f16x8*)(Wt16 + (nt * 16 + l15) * 256 + s * 32 + lq * 8);
        *(f16x8*)((char*)lds + (i * 256 + tid) * 16) = v;
    }
    __syncthreads();

    const char* bb = (const char*)lds + l * 16;
    f32x4 acc[4][4] = {};
    #pragma unroll
    for (int s = 0; s < 8; ++s) {
        f16x8 an[4];
        if (s < 7) {
            #pragma unroll
            for (int m = 0; m < 4; ++m) an[m] = *(const f16x8*)(ap[m] + (s + 1) * 32);
        }
        #pragma unroll
        for (int nt = 0; nt < 4; ++nt) {
            f16x8 b = *(const f16x8*)(bb + nt * 8192 + s * 1024);
            #pragma unroll
            for (int m = 0; m < 4; ++m)
                acc[m][nt] = __builtin_amdgcn_mfma_f32_16x16x32_f16(ac[m], b, acc[m][nt], 0, 0, 0);
        }
        if (s < 7) {
            #pragma unroll
            for (int m = 0; m < 4; ++m) ac[m] = an[m];
        }
    }

    float bsv[4];
    #pragma unroll
    for (int nt = 0; nt < 4; ++nt) {
        int col = nt * 16 + l15;
        bsv[nt] = b_s[col] + b_t[col];
    }
    #pragma unroll
    for (int m = 0; m < 4; ++m)
        #pragma unroll
        for (int j = 0; j < 4; ++j) {
            int r = rowbase + m * 16 + lq * 4 + j;
            #pragma unroll
            for (int nt = 0; nt < 4; ++nt)
                tl[r * 64 + nt * 16 + l15] = acc[m][nt][j] + bsv[nt];
        }
}

// ---------------------------------------------------------------------------
// main: GEMM [524288 x 256] x [256 x 128] + softmax epilogue
// 2048 blocks x 512 thr (8 waves). Block: 256 rows x 128 cols; wave: 32 rows.
// LDS: 64 fragments (nt<8, s<8) x 64 lanes x 16B = 64 KiB, fragment-major.
// K-loop: ds_read_b128 at shared base + immediate offset (conflict-free,
// no per-read VALU); A gather double-buffered one step ahead.
// ---------------------------------------------------------------------------
__global__ __launch_bounds__(512, 4)
void main_kernel(const _Float16* __restrict__ src16, const int* __restrict__ neighbors,
                 const _Float16* __restrict__ WcT, const float* __restrict__ tl,
                 const float* __restrict__ bmean, float* __restrict__ out) {
    __shared__ _Float16 lds[32768];   // 64 KiB

    const int tid = threadIdx.x;
    const int w = tid >> 6, l = tid & 63;
    const int l15 = l & 15, lq = l >> 4;
    const int rowbase = blockIdx.x * 256 + w * 32;

    // A gather pointers; issue step-0 loads before staging so they fly
    // during the barrier.
    const int r0 = rowbase + l15;
    const int r1 = rowbase + 16 + l15;
    const _Float16* ap0 = src16 + (size_t)neighbors[r0] * 256 + lq * 8;
    const _Float16* ap1 = src16 + (size_t)neighbors[r1] * 256 + lq * 8;
    f16x8 a0c = *(const f16x8*)ap0;
    f16x8 a1c = *(const f16x8*)ap1;

    // stage B fragment-major: wave w, iter i stages fragment fi = i*8 + w
    #pragma unroll
    for (int i = 0; i < 8; ++i) {
        int fi = i * 8 + w;
        int nt = fi >> 3, s = fi & 7;
        f16x8 v = *(const f16x8*)(WcT + (nt * 16 + l15) * 256 + s * 32 + lq * 8);
        *(f16x8*)((char*)lds + (i * 512 + tid) * 16) = v;
    }
    __syncthreads();

    const char* bb = (const char*)lds + l * 16;
    f32x4 acc[2][8] = {};

    #pragma unroll
    for (int s = 0; s < 8; ++s) {
        f16x8 a0n, a1n;
        if (s < 7) {
            a0n = *(const f16x8*)(ap0 + (s + 1) * 32);
            a1n = *(const f16x8*)(ap1 + (s + 1) * 32);
        }
        #pragma unroll
        for (int nt = 0; nt < 8; ++nt) {
            f16x8 b = *(const f16x8*)(bb + nt * 8192 + s * 1024);
            acc[0][nt] = __builtin_amdgcn_mfma_f32_16x16x32_f16(a0c, b, acc[0][nt], 0, 0, 0);
            acc[1][nt] = __builtin_amdgcn_mfma_f32_16x16x32_f16(a1c, b, acc[1][nt], 0, 0, 0);
        }
        if (s < 7) { a0c = a0n; a1c = a1n; }
    }

    // ---- epilogue: softmax over 64 logit cols, multiply proj, store ----
    const int n = blockIdx.x * 8 + w;           // one target node per wave
    float tlv[4], bmv[4];
    #pragma unroll
    for (int nt = 0; nt < 4; ++nt) {
        tlv[nt] = tl[n * 64 + nt * 16 + l15];
        bmv[nt] = bmean[nt * 16 + l15];
    }

    #pragma unroll
    for (int m = 0; m < 2; ++m) {
        #pragma unroll
        for (int j = 0; j < 4; ++j) {
            const int r = rowbase + m * 16 + lq * 4 + j;
            float lg[4];
            float mx = -1e30f;
            #pragma unroll
            for (int nt = 0; nt < 4; ++nt) {
                lg[nt] = acc[m][nt][j] + tlv[nt];
                mx = fmaxf(mx, lg[nt]);
            }
            #pragma unroll
            for (int d = 1; d < 16; d <<= 1) mx = fmaxf(mx, __shfl_xor(mx, d));
            float e[4], sum = 0.f;
            #pragma unroll
            for (int nt = 0; nt < 4; ++nt) {
                e[nt] = __expf(lg[nt] - mx);
                sum += e[nt];
            }
            #pragma unroll
            for (int d = 1; d < 16; d <<= 1) sum += __shfl_xor(sum, d);
            const float inv = 1.0f / sum;
            float* orow = out + (size_t)r * 64;
            #pragma unroll
            for (int nt = 0; nt < 4; ++nt) {
                float a = e[nt] * inv;
                orow[nt * 16 + l15] = a * (acc[m][nt + 4][j] + bmv[nt]);
            }
        }
    }
}

// ---------------------------------------------------------------------------
extern "C" void kernel_launch(void* const* d_in, const int* in_sizes, int n_in,
                              void* d_out, int out_size, void* d_ws, size_t ws_size,
                              hipStream_t stream) {
    const float* source    = (const float*)d_in[0];
    const float* target    = (const float*)d_in[1];
    const int*   neighbors = (const int*)d_in[2];
    const float* W_lin     = (const float*)d_in[3];
    const float* b_lin     = (const float*)d_in[4];
    const float* W_s       = (const float*)d_in[5];
    const float* b_s       = (const float*)d_in[6];
    const float* W_t       = (const float*)d_in[7];
    const float* b_t       = (const float*)d_in[8];

    char* ws = (char*)d_ws;
    _Float16* src16 = (_Float16*)ws;                          // 8 MiB
    _Float16* tgt16 = (_Float16*)(ws + (8u << 20));           // 8 MiB
    _Float16* WcT   = (_Float16*)(ws + (16u << 20));          // 64 KiB
    _Float16* Wt16  = (_Float16*)(ws + (16u << 20) + 65536);  // 32 KiB
    float*    bmean = (float*)(ws + (16u << 20) + 98304);     // 256 B
    float*    tl    = (float*)(ws + (16u << 20) + 98560);     // 4 MiB
    float*    out   = (float*)d_out;

    cvt_f16<<<2048, 256, 0, stream>>>(source, src16);
    cvt_f16<<<2048, 256, 0, stream>>>(target, tgt16);
    prep_weights<<<128, 256, 0, stream>>>(W_lin, b_lin, W_s, W_t, WcT, Wt16, bmean);
    prep_tl<<<64, 256, 0, stream>>>(tgt16, Wt16, b_s, b_t, tl);
    main_kernel<<<2048, 512, 0, stream>>>(src16, neighbors, WcT, tl, bmean, out);
}